// Round 12
// baseline (93.689 us; speedup 1.0000x reference)
//
#include <hip/hip_runtime.h>
#include <hip/hip_bf16.h>

#define SEQ 1024

typedef __attribute__((ext_vector_type(8))) short s16x8;
typedef __attribute__((ext_vector_type(4))) float f32x4;
typedef __attribute__((ext_vector_type(2))) unsigned int u32x2;
typedef __attribute__((ext_vector_type(4))) unsigned int u32x4;
typedef __attribute__((ext_vector_type(2))) float f32x2;

// bf16 element offsets in workspace
//  P01[v0][v1][512] = b1 + G0[v0] + G1[v1]   (index 38 = zero/pad row)
//  G2 [v][512]
//  P34[v3][v4][512] = G3[v3] + G4[v4]
#define P01P 0
#define G2P  (1521 * 512)
#define P34P (G2P + 39 * 512)
#define W2P  (P34P + 1521 * 512)
#define W3P  (W2P + 256 * 512)
#define W4P  (W3P + 64 * 512)

#define F2 (16 * 16)
#define F3 (8 * 8)
#define F4 (3 * 4)
#define FTOT (F2 + F3 + F4)
#define PAIR_BLOCKS 100            // 10x10 tiles of 4x4 (va,vb)

__device__ __forceinline__ unsigned int f2bf(float f) {
    unsigned int u = __float_as_uint(f);
    return (u + 0x7fffu + ((u >> 16) & 1u)) >> 16;   // RNE
}

__device__ __forceinline__ unsigned short bfbits(float f) {
    __hip_bfloat16 h = __float2bfloat16(f);
    unsigned short u;
    __builtin_memcpy(&u, &h, 2);
    return u;
}

__device__ __forceinline__ unsigned pk2(float a, float b) {
    return (unsigned)bfbits(a) | ((unsigned)bfbits(b) << 16);
}

__device__ __forceinline__ float bf2f(short x) {
    return __uint_as_float(((unsigned)(unsigned short)x) << 16);
}

__device__ __forceinline__ float dot4(float4 a, float4 b) {
    return a.x * b.x + a.y * b.y + a.z * b.z + a.w * b.w;
}

// single prep kernel:
//  blocks [0,100): direct pair tables. gx=bid/10 -> va0=gx*4; gy=bid%10 -> vb0=gy*4.
//    thread o (0..511): da[i]=W1[o][0:128]·emb[va0+i], db[j]=W1[o][128:256]·emb[vb0+j],
//                       dc[i]=W1[o][384:512]·emb[va0+i], dd[j]=W1[o][512:640]·emb[vb0+j]
//    P01[va,vb][o]=bfbits(b1[o]+da+db); P34=bfbits(dc+dd); gy==0 also G2[va][o].
//  blocks [100,142): pack W2/3/4 MFMA fragments.
__global__ void prep(const float* __restrict__ w1, const float* __restrict__ w2,
                     const float* __restrict__ w3, const float* __restrict__ w4,
                     const float* __restrict__ emb, const float* __restrict__ b1,
                     unsigned short* __restrict__ dst) {
    if (blockIdx.x < PAIR_BLOCKS) {
        __shared__ float eva[4][128];
        __shared__ float evb[4][128];
        const int gx = blockIdx.x / 10, gy = blockIdx.x % 10;
        const int va0 = gx * 4, vb0 = gy * 4;
        const int tid = threadIdx.x;
        // stage 4+4 embedding rows (v>=38 -> zero)
        for (int k = tid; k < 1024; k += 512) {
            const int half = k >> 9;           // 0: eva, 1: evb
            const int row  = (k >> 7) & 3;
            const int d    = k & 127;
            const int v    = (half ? vb0 : va0) + row;
            const float f  = (v < 38) ? emb[v * 128 + d] : 0.f;
            if (half) evb[row][d] = f; else eva[row][d] = f;
        }
        __syncthreads();

        const int o = tid;
        const float* w = w1 + o * 640;
        float da[4] = {0, 0, 0, 0}, db[4] = {0, 0, 0, 0};
        float dc[4] = {0, 0, 0, 0}, dd[4] = {0, 0, 0, 0};
        float dg[4] = {0, 0, 0, 0};
        const bool doG2 = (gy == 0);
        for (int d = 0; d < 128; d += 4) {
            const float4 wa = *reinterpret_cast<const float4*>(w + d);
            const float4 wb = *reinterpret_cast<const float4*>(w + 128 + d);
            const float4 wc = *reinterpret_cast<const float4*>(w + 384 + d);
            const float4 wd = *reinterpret_cast<const float4*>(w + 512 + d);
            float4 wg;
            if (doG2) wg = *reinterpret_cast<const float4*>(w + 256 + d);
            #pragma unroll
            for (int i = 0; i < 4; ++i) {
                const float4 ea = *reinterpret_cast<const float4*>(&eva[i][d]);
                const float4 eb = *reinterpret_cast<const float4*>(&evb[i][d]);
                da[i] += dot4(wa, ea);
                db[i] += dot4(wb, eb);
                dc[i] += dot4(wc, ea);
                dd[i] += dot4(wd, eb);
                if (doG2) dg[i] += dot4(wg, ea);
            }
        }
        const float b1o = b1[o];
        #pragma unroll
        for (int i = 0; i < 4; ++i) {
            const int va = va0 + i;
            if (va >= 39) continue;
            #pragma unroll
            for (int j = 0; j < 4; ++j) {
                const int vb = vb0 + j;
                if (vb >= 39) continue;
                dst[P01P + (va * 39 + vb) * 512 + o] = bfbits(b1o + da[i] + db[j]);
                dst[P34P + (va * 39 + vb) * 512 + o] = bfbits(dc[i] + dd[j]);
            }
            if (doG2) dst[G2P + va * 512 + o] = bfbits(dg[i]);
        }
    } else {
        const int g = (blockIdx.x - PAIR_BLOCKS) * 512 + threadIdx.x;
        if (g >= FTOT * 64) return;
        const int lane = g & 63;
        const int t    = g >> 6;
        const float* w; int K, N, KC, base, tl;
        if (t < F2)           { w = w2; K = 512; N = 256; KC = 16; base = W2P; tl = t; }
        else if (t < F2 + F3) { w = w3; K = 256; N = 128; KC = 8;  base = W3P; tl = t - F2; }
        else                  { w = w4; K = 128; N = 38;  KC = 4;  base = W4P; tl = t - F2 - F3; }
        const int ct  = tl / KC;
        const int kc  = tl - ct * KC;
        const int col = ct * 16 + (lane & 15);
        const int k0  = kc * 32 + (lane >> 4) * 8;
        unsigned short o8[8];
        #pragma unroll
        for (int e = 0; e < 8; ++e)
            o8[e] = (col < N) ? (unsigned short)f2bf(w[col * K + k0 + e]) : (unsigned short)0;
        *reinterpret_cast<s16x8*>(dst + base + (size_t)(tl * 64 + lane) * 8) =
            *reinterpret_cast<s16x8*>(o8);
    }
}

// LDS (64.5 KB, 512 threads, M=64, 2 blocks/CU)  -- R9's verified fused kernel
#define BA 0
#define BB 32768
#define TOKO 65536

#define SWZ(b, row) ((b) ^ (((row) & 15) << 4))

__device__ __forceinline__ u32x2 pack_relu(f32x4 a, float4 b) {
    u32x2 r;
    r[0] = pk2(fmaxf(a[0] + b.x, 0.f), fmaxf(a[1] + b.y, 0.f));
    r[1] = pk2(fmaxf(a[2] + b.z, 0.f), fmaxf(a[3] + b.w, 0.f));
    return r;
}

__launch_bounds__(512, 4)
__global__ void fused_mlp(const int* __restrict__ tok,
                          const unsigned short* __restrict__ wbf,
                          const float* __restrict__ b2,
                          const float* __restrict__ b3,
                          const float* __restrict__ b4,
                          float* __restrict__ out) {
    __shared__ char smem[65536 + 512];
    const int tid  = threadIdx.x;
    const int lane = tid & 63;
    const int wave = tid >> 6;                 // 0..7
    const int l15  = lane & 15;
    const int l4   = lane >> 4;                // 0..3
    const int r0   = blockIdx.x * 64;
    const int s0   = r0 & (SEQ - 1);
    const int bat  = r0 >> 10;

    int* tokL = reinterpret_cast<int*>(smem + TOKO);

    if (tid < 68) {
        const int sp = s0 - 2 + tid;
        tokL[tid] = (sp >= 0 && sp < SEQ) ? tok[bat * SEQ + sp] : 38;
    }
    __syncthreads();

    const int p1row = tid >> 3;
    const int p1c   = tid & 7;
    int off01, off2, off34;
    {
        const int t0 = tokL[p1row],     t1 = tokL[p1row + 1], t2 = tokL[p1row + 2];
        const int t3 = tokL[p1row + 3], t4 = tokL[p1row + 4];
        off01 = (t0 * 39 + t1) * 512;
        off2  = t2 * 512;
        off34 = (t3 * 39 + t4) * 512;
    }

    // ---------- phase 1a: h1 dims [0,256) -> buf A
    #pragma unroll
    for (int it = 0; it < 4; ++it) {
        const int c8 = it * 8 + p1c;
        const int d  = c8 * 8;
        const s16x8 va = *reinterpret_cast<const s16x8*>(wbf + P01P + off01 + d);
        const s16x8 vb = *reinterpret_cast<const s16x8*>(wbf + G2P  + off2  + d);
        const s16x8 vc = *reinterpret_cast<const s16x8*>(wbf + P34P + off34 + d);
        u32x4 wv;
        #pragma unroll
        for (int h = 0; h < 4; ++h) {
            const float e0 = bf2f(va[2 * h])     + bf2f(vb[2 * h])     + bf2f(vc[2 * h]);
            const float e1 = bf2f(va[2 * h + 1]) + bf2f(vb[2 * h + 1]) + bf2f(vc[2 * h + 1]);
            wv[h] = pk2(fmaxf(e0, 0.f), fmaxf(e1, 0.f));
        }
        *reinterpret_cast<u32x4*>(smem + BA + SWZ(p1row * 512 + c8 * 16, p1row)) = wv;
    }
    __syncthreads();

    // ---------- GEMM2 part A (ks 0..7 from buf A) + phase 1b (dims [256,512) -> buf B)
    f32x4 acc2[4][2];
    #pragma unroll
    for (int rt = 0; rt < 4; ++rt)
        #pragma unroll
        for (int ct = 0; ct < 2; ++ct) acc2[rt][ct] = (f32x4){0.f, 0.f, 0.f, 0.f};
    {
        #pragma unroll
        for (int it = 0; it < 4; ++it) {
            const int c8 = it * 8 + p1c;
            const int d  = 256 + c8 * 8;
            const s16x8 va = *reinterpret_cast<const s16x8*>(wbf + P01P + off01 + d);
            const s16x8 vb = *reinterpret_cast<const s16x8*>(wbf + G2P  + off2  + d);
            const s16x8 vc = *reinterpret_cast<const s16x8*>(wbf + P34P + off34 + d);
            u32x4 wv;
            #pragma unroll
            for (int h = 0; h < 4; ++h) {
                const float e0 = bf2f(va[2 * h])     + bf2f(vb[2 * h])     + bf2f(vc[2 * h]);
                const float e1 = bf2f(va[2 * h + 1]) + bf2f(vb[2 * h + 1]) + bf2f(vc[2 * h + 1]);
                wv[h] = pk2(fmaxf(e0, 0.f), fmaxf(e1, 0.f));
            }
            *reinterpret_cast<u32x4*>(smem + BB + SWZ(p1row * 512 + c8 * 16, p1row)) = wv;
        }
        for (int ks = 0; ks < 8; ++ks) {
            s16x8 xv[4];
            #pragma unroll
            for (int rt = 0; rt < 4; ++rt) {
                const int row = rt * 16 + l15;
                xv[rt] = *reinterpret_cast<const s16x8*>(
                    smem + BA + SWZ(row * 512 + ks * 64 + l4 * 16, row));
            }
            #pragma unroll
            for (int ct = 0; ct < 2; ++ct) {
                const s16x8 w = *reinterpret_cast<const s16x8*>(
                    wbf + W2P + (((wave * 2 + ct) * 16 + ks) * 64 + lane) * 8);
                #pragma unroll
                for (int rt = 0; rt < 4; ++rt)
                    acc2[rt][ct] = __builtin_amdgcn_mfma_f32_16x16x32_bf16(w, xv[rt], acc2[rt][ct], 0, 0, 0);
            }
        }
    }
    __syncthreads();

    // ---------- GEMM2 part B (ks 8..15 from buf B) + epilogue -> h2 in buf A
    {
        for (int ks = 0; ks < 8; ++ks) {
            s16x8 xv[4];
            #pragma unroll
            for (int rt = 0; rt < 4; ++rt) {
                const int row = rt * 16 + l15;
                xv[rt] = *reinterpret_cast<const s16x8*>(
                    smem + BB + SWZ(row * 512 + ks * 64 + l4 * 16, row));
            }
            #pragma unroll
            for (int ct = 0; ct < 2; ++ct) {
                const s16x8 w = *reinterpret_cast<const s16x8*>(
                    wbf + W2P + (((wave * 2 + ct) * 16 + 8 + ks) * 64 + lane) * 8);
                #pragma unroll
                for (int rt = 0; rt < 4; ++rt)
                    acc2[rt][ct] = __builtin_amdgcn_mfma_f32_16x16x32_bf16(w, xv[rt], acc2[rt][ct], 0, 0, 0);
            }
        }
        #pragma unroll
        for (int ct = 0; ct < 2; ++ct) {
            const int col0 = (wave * 2 + ct) * 16 + l4 * 4;
            const float4 bb = *reinterpret_cast<const float4*>(b2 + col0);
            #pragma unroll
            for (int rt = 0; rt < 4; ++rt) {
                const int row = rt * 16 + l15;
                *reinterpret_cast<u32x2*>(smem + BA + SWZ(row * 512 + col0 * 2, row)) =
                    pack_relu(acc2[rt][ct], bb);
            }
        }
    }
    __syncthreads();

    // ---------- GEMM3: [64,256] -> [64,128]; wave=ct, 4 row-tiles; h3 -> buf B
    {
        f32x4 acc[4];
        #pragma unroll
        for (int rt = 0; rt < 4; ++rt) acc[rt] = (f32x4){0.f, 0.f, 0.f, 0.f};
        for (int ks = 0; ks < 8; ++ks) {
            const s16x8 w = *reinterpret_cast<const s16x8*>(
                wbf + W3P + ((wave * 8 + ks) * 64 + lane) * 8);
            #pragma unroll
            for (int rt = 0; rt < 4; ++rt) {
                const int row = rt * 16 + l15;
                const s16x8 xv = *reinterpret_cast<const s16x8*>(
                    smem + BA + SWZ(row * 512 + ks * 64 + l4 * 16, row));
                acc[rt] = __builtin_amdgcn_mfma_f32_16x16x32_bf16(w, xv, acc[rt], 0, 0, 0);
            }
        }
        const int col0 = wave * 16 + l4 * 4;
        const float4 bb = *reinterpret_cast<const float4*>(b3 + col0);
        #pragma unroll
        for (int rt = 0; rt < 4; ++rt) {
            const int row = rt * 16 + l15;
            *reinterpret_cast<u32x2*>(smem + BB + SWZ(row * 256 + col0 * 2, row)) =
                pack_relu(acc[rt], bb);
        }
    }
    __syncthreads();

    // ---------- GEMM4: [64,128] -> out[64,38]; 12 tasks over 8 waves
    for (int task = wave; task < 12; task += 8) {
        const int mt = task >> 2;
        const int rt = task & 3;
        f32x4 acc = (f32x4){0.f, 0.f, 0.f, 0.f};
        #pragma unroll
        for (int ks = 0; ks < 4; ++ks) {
            const int row = rt * 16 + l15;
            const s16x8 xv = *reinterpret_cast<const s16x8*>(
                smem + BB + SWZ(row * 256 + ks * 64 + l4 * 16, row));
            const s16x8 w = *reinterpret_cast<const s16x8*>(
                wbf + W4P + ((mt * 4 + ks) * 64 + lane) * 8);
            acc = __builtin_amdgcn_mfma_f32_16x16x32_bf16(w, xv, acc, 0, 0, 0);
        }
        const int rg   = r0 + rt * 16 + l15;
        const int col0 = mt * 16 + l4 * 4;
        #pragma unroll
        for (int h = 0; h < 2; ++h) {
            const int c = col0 + 2 * h;
            if (c < 38) {
                f32x2 v;
                v[0] = acc[2 * h]     + b4[c];
                v[1] = acc[2 * h + 1] + b4[c + 1];
                *reinterpret_cast<f32x2*>(out + rg * 38 + c) = v;
            }
        }
    }
}

extern "C" void kernel_launch(void* const* d_in, const int* in_sizes, int n_in,
                              void* d_out, int out_size, void* d_ws, size_t ws_size,
                              hipStream_t stream) {
    const int*   tok = (const int*)d_in[0];
    const float* emb = (const float*)d_in[1];
    const float* W1  = (const float*)d_in[2];
    const float* b1  = (const float*)d_in[3];
    const float* W2  = (const float*)d_in[4];
    const float* b2  = (const float*)d_in[5];
    const float* W3  = (const float*)d_in[6];
    const float* b3  = (const float*)d_in[7];
    const float* W4  = (const float*)d_in[8];
    const float* b4  = (const float*)d_in[9];
    float* out = (float*)d_out;
    unsigned short* wbf = (unsigned short*)d_ws;

    const int pack_blocks = (FTOT * 64 + 511) / 512;     // 42
    prep<<<PAIR_BLOCKS + pack_blocks, 512, 0, stream>>>(W1, W2, W3, W4, emb, b1, wbf);
    fused_mlp<<<1024, 512, 0, stream>>>(tok, wbf, b2, b3, b4, out);
}

// Round 13
// 51.427 us; speedup vs baseline: 1.8218x; 1.8218x over previous
//
#include <hip/hip_runtime.h>
#include <hip/hip_bf16.h>

#define SEQ 1024

typedef __attribute__((ext_vector_type(8))) short s16x8;
typedef __attribute__((ext_vector_type(4))) float f32x4;
typedef __attribute__((ext_vector_type(2))) unsigned int u32x2;
typedef __attribute__((ext_vector_type(4))) unsigned int u32x4;
typedef __attribute__((ext_vector_type(2))) float f32x2;

// bf16 element offsets in workspace
//  G[j][v][512] = W1[:, j*128:(j+1)*128] · emb[v]   (v=38 is the zero/pad row) -- 200KB, L2-hot
#define GT  0
#define W2P (5 * 39 * 512)
#define W3P (W2P + 256 * 512)
#define W4P (W3P + 64 * 512)

#define F2 (16 * 16)
#define F3 (8 * 8)
#define F4 (3 * 4)
#define FTOT (F2 + F3 + F4)

__device__ __forceinline__ unsigned int f2bf(float f) {
    unsigned int u = __float_as_uint(f);
    return (u + 0x7fffu + ((u >> 16) & 1u)) >> 16;   // RNE
}

__device__ __forceinline__ unsigned short bfbits(float f) {
    __hip_bfloat16 h = __float2bfloat16(f);
    unsigned short u;
    __builtin_memcpy(&u, &h, 2);
    return u;
}

__device__ __forceinline__ unsigned pk2(float a, float b) {
    return (unsigned)bfbits(a) | ((unsigned)bfbits(b) << 16);
}

__device__ __forceinline__ float bf2f(short x) {
    return __uint_as_float(((unsigned)(unsigned short)x) << 16);
}

// prep (R7-proven): blocks [0,195) -> bf16 G[j][v][o]; blocks [195,237) pack W2/3/4 frags
__global__ void prep(const float* __restrict__ w1, const float* __restrict__ w2,
                     const float* __restrict__ w3, const float* __restrict__ w4,
                     const float* __restrict__ emb, unsigned short* __restrict__ dst) {
    if (blockIdx.x < 195) {
        const int j = blockIdx.x / 39;
        const int v = blockIdx.x % 39;
        const int o = threadIdx.x;               // 0..511
        if (v >= 38) { dst[GT + (j * 39 + v) * 512 + o] = 0; return; }
        __shared__ float ev[128];
        if (threadIdx.x < 128) ev[threadIdx.x] = emb[v * 128 + threadIdx.x];
        __syncthreads();
        const float* wr = w1 + o * 640 + j * 128;
        float s = 0.f;
        #pragma unroll
        for (int e = 0; e < 128; e += 4) {
            const float4 a = *reinterpret_cast<const float4*>(wr + e);
            s += a.x * ev[e] + a.y * ev[e + 1] + a.z * ev[e + 2] + a.w * ev[e + 3];
        }
        dst[GT + (j * 39 + v) * 512 + o] = bfbits(s);
    } else {
        const int g = (blockIdx.x - 195) * 512 + threadIdx.x;
        if (g >= FTOT * 64) return;
        const int lane = g & 63;
        const int t    = g >> 6;
        const float* w; int K, N, KC, base, tl;
        if (t < F2)           { w = w2; K = 512; N = 256; KC = 16; base = W2P; tl = t; }
        else if (t < F2 + F3) { w = w3; K = 256; N = 128; KC = 8;  base = W3P; tl = t - F2; }
        else                  { w = w4; K = 128; N = 38;  KC = 4;  base = W4P; tl = t - F2 - F3; }
        const int ct  = tl / KC;
        const int kc  = tl - ct * KC;
        const int col = ct * 16 + (lane & 15);
        const int k0  = kc * 32 + (lane >> 4) * 8;
        unsigned short o8[8];
        #pragma unroll
        for (int e = 0; e < 8; ++e)
            o8[e] = (col < N) ? (unsigned short)f2bf(w[col * K + k0 + e]) : (unsigned short)0;
        *reinterpret_cast<s16x8*>(dst + base + (size_t)(tl * 64 + lane) * 8) =
            *reinterpret_cast<s16x8*>(o8);
    }
}

// LDS (64 KB, 512 threads, M=64, 2 blocks/CU):
//   buf A @ 0     (32768): h1 dims [0,256)   -> h2 (64 x 256, stride 512B)
//   buf B @ 32768 (32768): h1 dims [256,512) -> h3 (64 x 128, stride 256B)
#define BA 0
#define BB 32768

#define SWZ(b, row) ((b) ^ (((row) & 15) << 4))

__device__ __forceinline__ u32x2 pack_relu(f32x4 a, float4 b) {
    u32x2 r;
    r[0] = pk2(fmaxf(a[0] + b.x, 0.f), fmaxf(a[1] + b.y, 0.f));
    r[1] = pk2(fmaxf(a[2] + b.z, 0.f), fmaxf(a[3] + b.w, 0.f));
    return r;
}

__launch_bounds__(512, 4)
__global__ void fused_mlp(const int* __restrict__ tok,
                          const unsigned short* __restrict__ wbf,
                          const float* __restrict__ b1,
                          const float* __restrict__ b2,
                          const float* __restrict__ b3,
                          const float* __restrict__ b4,
                          float* __restrict__ out) {
    __shared__ char smem[65536];
    const int tid  = threadIdx.x;
    const int lane = tid & 63;
    const int wave = tid >> 6;                 // 0..7
    const int l15  = lane & 15;
    const int l4   = lane >> 4;                // 0..3
    const int r0   = blockIdx.x * 64;
    const int s0   = r0 & (SEQ - 1);
    const int bat  = r0 >> 10;

    // per-thread context tokens (8 threads/row share -> L1 broadcast); OOB -> 38 (zero G row)
    const int p1row = tid >> 3;                // 0..63
    const int p1c   = tid & 7;
    int goff[5];
    #pragma unroll
    for (int j = 0; j < 5; ++j) {
        const int sp = s0 - 2 + p1row + j;
        const int t  = (sp >= 0 && sp < SEQ) ? tok[bat * SEQ + sp] : 38;
        goff[j] = (j * 39 + t) * 512;
    }

    // ---------- phase 1a: h1 dims [0,256) = relu(b1 + sum_j G[j][t_j]) -> buf A
    #pragma unroll
    for (int it = 0; it < 4; ++it) {
        const int c8 = it * 8 + p1c;           // 0..31 (8-dim chunk in half)
        const int d  = c8 * 8;
        s16x8 g[5];
        #pragma unroll
        for (int j = 0; j < 5; ++j)
            g[j] = *reinterpret_cast<const s16x8*>(wbf + GT + goff[j] + d);
        const float4 blo = *reinterpret_cast<const float4*>(b1 + d);
        const float4 bhi = *reinterpret_cast<const float4*>(b1 + d + 4);
        float s[8] = {blo.x, blo.y, blo.z, blo.w, bhi.x, bhi.y, bhi.z, bhi.w};
        #pragma unroll
        for (int j = 0; j < 5; ++j)
            #pragma unroll
            for (int e = 0; e < 8; ++e)
                s[e] += bf2f(g[j][e]);
        u32x4 wv;
        #pragma unroll
        for (int h = 0; h < 4; ++h)
            wv[h] = pk2(fmaxf(s[2 * h], 0.f), fmaxf(s[2 * h + 1], 0.f));
        *reinterpret_cast<u32x4*>(smem + BA + SWZ(p1row * 512 + c8 * 16, p1row)) = wv;
    }
    __syncthreads();

    // ---------- GEMM2 part A (ks 0..7 from buf A) + phase 1b (dims [256,512) -> buf B)
    f32x4 acc2[4][2];
    #pragma unroll
    for (int rt = 0; rt < 4; ++rt)
        #pragma unroll
        for (int ct = 0; ct < 2; ++ct) acc2[rt][ct] = (f32x4){0.f, 0.f, 0.f, 0.f};
    {
        #pragma unroll
        for (int it = 0; it < 4; ++it) {
            const int c8 = it * 8 + p1c;
            const int d  = 256 + c8 * 8;
            s16x8 g[5];
            #pragma unroll
            for (int j = 0; j < 5; ++j)
                g[j] = *reinterpret_cast<const s16x8*>(wbf + GT + goff[j] + d);
            const float4 blo = *reinterpret_cast<const float4*>(b1 + d);
            const float4 bhi = *reinterpret_cast<const float4*>(b1 + d + 4);
            float s[8] = {blo.x, blo.y, blo.z, blo.w, bhi.x, bhi.y, bhi.z, bhi.w};
            #pragma unroll
            for (int j = 0; j < 5; ++j)
                #pragma unroll
                for (int e = 0; e < 8; ++e)
                    s[e] += bf2f(g[j][e]);
            u32x4 wv;
            #pragma unroll
            for (int h = 0; h < 4; ++h)
                wv[h] = pk2(fmaxf(s[2 * h], 0.f), fmaxf(s[2 * h + 1], 0.f));
            *reinterpret_cast<u32x4*>(smem + BB + SWZ(p1row * 512 + c8 * 16, p1row)) = wv;
        }
        for (int ks = 0; ks < 8; ++ks) {
            s16x8 xv[4];
            #pragma unroll
            for (int rt = 0; rt < 4; ++rt) {
                const int row = rt * 16 + l15;
                xv[rt] = *reinterpret_cast<const s16x8*>(
                    smem + BA + SWZ(row * 512 + ks * 64 + l4 * 16, row));
            }
            __builtin_amdgcn_s_setprio(1);
            #pragma unroll
            for (int ct = 0; ct < 2; ++ct) {
                const s16x8 w = *reinterpret_cast<const s16x8*>(
                    wbf + W2P + (((wave * 2 + ct) * 16 + ks) * 64 + lane) * 8);
                #pragma unroll
                for (int rt = 0; rt < 4; ++rt)
                    acc2[rt][ct] = __builtin_amdgcn_mfma_f32_16x16x32_bf16(w, xv[rt], acc2[rt][ct], 0, 0, 0);
            }
            __builtin_amdgcn_s_setprio(0);
        }
    }
    __syncthreads();

    // ---------- GEMM2 part B (ks 8..15 from buf B) + epilogue -> h2 in buf A
    {
        for (int ks = 0; ks < 8; ++ks) {
            s16x8 xv[4];
            #pragma unroll
            for (int rt = 0; rt < 4; ++rt) {
                const int row = rt * 16 + l15;
                xv[rt] = *reinterpret_cast<const s16x8*>(
                    smem + BB + SWZ(row * 512 + ks * 64 + l4 * 16, row));
            }
            __builtin_amdgcn_s_setprio(1);
            #pragma unroll
            for (int ct = 0; ct < 2; ++ct) {
                const s16x8 w = *reinterpret_cast<const s16x8*>(
                    wbf + W2P + (((wave * 2 + ct) * 16 + 8 + ks) * 64 + lane) * 8);
                #pragma unroll
                for (int rt = 0; rt < 4; ++rt)
                    acc2[rt][ct] = __builtin_amdgcn_mfma_f32_16x16x32_bf16(w, xv[rt], acc2[rt][ct], 0, 0, 0);
            }
            __builtin_amdgcn_s_setprio(0);
        }
        #pragma unroll
        for (int ct = 0; ct < 2; ++ct) {
            const int col0 = (wave * 2 + ct) * 16 + l4 * 4;
            const float4 bb = *reinterpret_cast<const float4*>(b2 + col0);
            #pragma unroll
            for (int rt = 0; rt < 4; ++rt) {
                const int row = rt * 16 + l15;
                *reinterpret_cast<u32x2*>(smem + BA + SWZ(row * 512 + col0 * 2, row)) =
                    pack_relu(acc2[rt][ct], bb);
            }
        }
    }
    __syncthreads();

    // ---------- GEMM3: [64,256] -> [64,128]; wave=ct, 4 row-tiles; h3 -> buf B
    {
        f32x4 acc[4];
        #pragma unroll
        for (int rt = 0; rt < 4; ++rt) acc[rt] = (f32x4){0.f, 0.f, 0.f, 0.f};
        for (int ks = 0; ks < 8; ++ks) {
            const s16x8 w = *reinterpret_cast<const s16x8*>(
                wbf + W3P + ((wave * 8 + ks) * 64 + lane) * 8);
            s16x8 xv[4];
            #pragma unroll
            for (int rt = 0; rt < 4; ++rt) {
                const int row = rt * 16 + l15;
                xv[rt] = *reinterpret_cast<const s16x8*>(
                    smem + BA + SWZ(row * 512 + ks * 64 + l4 * 16, row));
            }
            __builtin_amdgcn_s_setprio(1);
            #pragma unroll
            for (int rt = 0; rt < 4; ++rt)
                acc[rt] = __builtin_amdgcn_mfma_f32_16x16x32_bf16(w, xv[rt], acc[rt], 0, 0, 0);
            __builtin_amdgcn_s_setprio(0);
        }
        const int col0 = wave * 16 + l4 * 4;
        const float4 bb = *reinterpret_cast<const float4*>(b3 + col0);
        #pragma unroll
        for (int rt = 0; rt < 4; ++rt) {
            const int row = rt * 16 + l15;
            *reinterpret_cast<u32x2*>(smem + BB + SWZ(row * 256 + col0 * 2, row)) =
                pack_relu(acc[rt], bb);
        }
    }
    __syncthreads();

    // ---------- GEMM4: [64,128] -> out[64,38]; 12 tasks over 8 waves
    for (int task = wave; task < 12; task += 8) {
        const int mt = task >> 2;
        const int rt = task & 3;
        f32x4 acc = (f32x4){0.f, 0.f, 0.f, 0.f};
        #pragma unroll
        for (int ks = 0; ks < 4; ++ks) {
            const int row = rt * 16 + l15;
            const s16x8 xv = *reinterpret_cast<const s16x8*>(
                smem + BB + SWZ(row * 256 + ks * 64 + l4 * 16, row));
            const s16x8 w = *reinterpret_cast<const s16x8*>(
                wbf + W4P + ((mt * 4 + ks) * 64 + lane) * 8);
            acc = __builtin_amdgcn_mfma_f32_16x16x32_bf16(w, xv, acc, 0, 0, 0);
        }
        const int rg   = r0 + rt * 16 + l15;
        const int col0 = mt * 16 + l4 * 4;
        #pragma unroll
        for (int h = 0; h < 2; ++h) {
            const int c = col0 + 2 * h;
            if (c < 38) {
                f32x2 v;
                v[0] = acc[2 * h]     + b4[c];
                v[1] = acc[2 * h + 1] + b4[c + 1];
                *reinterpret_cast<f32x2*>(out + rg * 38 + c) = v;
            }
        }
    }
}

extern "C" void kernel_launch(void* const* d_in, const int* in_sizes, int n_in,
                              void* d_out, int out_size, void* d_ws, size_t ws_size,
                              hipStream_t stream) {
    const int*   tok = (const int*)d_in[0];
    const float* emb = (const float*)d_in[1];
    const float* W1  = (const float*)d_in[2];
    const float* b1  = (const float*)d_in[3];
    const float* W2  = (const float*)d_in[4];
    const float* b2  = (const float*)d_in[5];
    const float* W3  = (const float*)d_in[6];
    const float* b3  = (const float*)d_in[7];
    const float* W4  = (const float*)d_in[8];
    const float* b4  = (const float*)d_in[9];
    float* out = (float*)d_out;
    unsigned short* wbf = (unsigned short*)d_ws;

    const int pack_blocks = (FTOT * 64 + 511) / 512;     // 42
    prep<<<195 + pack_blocks, 512, 0, stream>>>(W1, W2, W3, W4, emb, wbf);
    fused_mlp<<<1024, 512, 0, stream>>>(tok, wbf, b1, b2, b3, b4, out);
}

// Round 14
// 49.117 us; speedup vs baseline: 1.9075x; 1.0470x over previous
//
#include <hip/hip_runtime.h>
#include <hip/hip_bf16.h>

#define SEQ 1024

typedef __attribute__((ext_vector_type(8))) short s16x8;
typedef __attribute__((ext_vector_type(4))) float f32x4;
typedef __attribute__((ext_vector_type(2))) unsigned int u32x2;
typedef __attribute__((ext_vector_type(4))) unsigned int u32x4;
typedef __attribute__((ext_vector_type(2))) float f32x2;

// bf16 element offsets in workspace
//  G[j][v][512]; G[0] has b1 folded in (incl. v=38 pad row -> b1); v=38 zero for j>0
#define GT  0
#define W2P (5 * 39 * 512)
#define W3P (W2P + 256 * 512)
#define W4P (W3P + 64 * 512)

#define F2 (16 * 16)
#define F3 (8 * 8)
#define F4 (3 * 4)
#define FTOT (F2 + F3 + F4)

__device__ __forceinline__ unsigned int f2bf(float f) {
    unsigned int u = __float_as_uint(f);
    return (u + 0x7fffu + ((u >> 16) & 1u)) >> 16;   // RNE
}

__device__ __forceinline__ unsigned short bfbits(float f) {
    __hip_bfloat16 h = __float2bfloat16(f);
    unsigned short u;
    __builtin_memcpy(&u, &h, 2);
    return u;
}

__device__ __forceinline__ unsigned pk2(float a, float b) {
    return (unsigned)bfbits(a) | ((unsigned)bfbits(b) << 16);
}

__device__ __forceinline__ float bf2f(short x) {
    return __uint_as_float(((unsigned)(unsigned short)x) << 16);
}

// unpack s16x8 (8 bf16) into 4 f32x2 pairs
__device__ __forceinline__ void cvt8(const s16x8 g, f32x2 o[4]) {
    #pragma unroll
    for (int h = 0; h < 4; ++h) {
        o[h][0] = bf2f(g[2 * h]);
        o[h][1] = bf2f(g[2 * h + 1]);
    }
}

// prep: blocks [0,195) -> bf16 G[j][v][o] (b1 folded into j==0); blocks [195,..) pack W2/3/4
__global__ void prep(const float* __restrict__ w1, const float* __restrict__ w2,
                     const float* __restrict__ w3, const float* __restrict__ w4,
                     const float* __restrict__ emb, const float* __restrict__ b1,
                     unsigned short* __restrict__ dst) {
    if (blockIdx.x < 195) {
        const int j = blockIdx.x / 39;
        const int v = blockIdx.x % 39;
        const int o = threadIdx.x;               // 0..511
        if (v >= 38) {                           // pad row: b1 for j==0 (bias applied once), else 0
            dst[GT + (j * 39 + v) * 512 + o] = (j == 0) ? bfbits(b1[o]) : (unsigned short)0;
            return;
        }
        __shared__ float ev[128];
        if (threadIdx.x < 128) ev[threadIdx.x] = emb[v * 128 + threadIdx.x];
        __syncthreads();
        const float* wr = w1 + o * 640 + j * 128;
        float s = (j == 0) ? b1[o] : 0.f;
        #pragma unroll
        for (int e = 0; e < 128; e += 4) {
            const float4 a = *reinterpret_cast<const float4*>(wr + e);
            s += a.x * ev[e] + a.y * ev[e + 1] + a.z * ev[e + 2] + a.w * ev[e + 3];
        }
        dst[GT + (j * 39 + v) * 512 + o] = bfbits(s);
    } else {
        const int g = (blockIdx.x - 195) * 512 + threadIdx.x;
        if (g >= FTOT * 64) return;
        const int lane = g & 63;
        const int t    = g >> 6;
        const float* w; int K, N, KC, base, tl;
        if (t < F2)           { w = w2; K = 512; N = 256; KC = 16; base = W2P; tl = t; }
        else if (t < F2 + F3) { w = w3; K = 256; N = 128; KC = 8;  base = W3P; tl = t - F2; }
        else                  { w = w4; K = 128; N = 38;  KC = 4;  base = W4P; tl = t - F2 - F3; }
        const int ct  = tl / KC;
        const int kc  = tl - ct * KC;
        const int col = ct * 16 + (lane & 15);
        const int k0  = kc * 32 + (lane >> 4) * 8;
        unsigned short o8[8];
        #pragma unroll
        for (int e = 0; e < 8; ++e)
            o8[e] = (col < N) ? (unsigned short)f2bf(w[col * K + k0 + e]) : (unsigned short)0;
        *reinterpret_cast<s16x8*>(dst + base + (size_t)(tl * 64 + lane) * 8) =
            *reinterpret_cast<s16x8*>(o8);
    }
}

// LDS (64 KB, 512 threads, M=64, 2 blocks/CU):
//   buf A @ 0     (32768): h1 dims [0,256)   -> h2 (64 x 256, stride 512B)
//   buf B @ 32768 (32768): h1 dims [256,512) -> h3 (64 x 128, stride 256B)
#define BA 0
#define BB 32768

#define SWZ(b, row) ((b) ^ (((row) & 15) << 4))

__device__ __forceinline__ u32x2 pack_relu(f32x4 a, float4 b) {
    u32x2 r;
    r[0] = pk2(fmaxf(a[0] + b.x, 0.f), fmaxf(a[1] + b.y, 0.f));
    r[1] = pk2(fmaxf(a[2] + b.z, 0.f), fmaxf(a[3] + b.w, 0.f));
    return r;
}

__launch_bounds__(512, 4)
__global__ void fused_mlp(const int* __restrict__ tok,
                          const unsigned short* __restrict__ wbf,
                          const float* __restrict__ b2,
                          const float* __restrict__ b3,
                          const float* __restrict__ b4,
                          float* __restrict__ out) {
    __shared__ char smem[65536];
    const int tid  = threadIdx.x;
    const int lane = tid & 63;
    const int wave = tid >> 6;                 // 0..7
    const int l15  = lane & 15;
    const int l4   = lane >> 4;                // 0..3
    const int r0   = blockIdx.x * 64;
    const int s0   = r0 & (SEQ - 1);
    const int bat  = r0 >> 10;

    // per-thread context tokens (8 threads/row share -> L1 broadcast); OOB -> 38
    const int p1row = tid >> 3;                // 0..63
    const int p1c   = tid & 7;
    int goff[5];
    #pragma unroll
    for (int j = 0; j < 5; ++j) {
        const int sp = s0 - 2 + p1row + j;
        const int t  = (sp >= 0 && sp < SEQ) ? tok[bat * SEQ + sp] : 38;
        goff[j] = (j * 39 + t) * 512;
    }

    // ---------- phase 1a: h1 dims [0,256) = relu(sum_j G[j][t_j]) -> buf A (b1 in G0)
    #pragma unroll
    for (int it = 0; it < 4; ++it) {
        const int c8 = it * 8 + p1c;           // 0..31
        const int d  = c8 * 8;
        s16x8 g[5];
        #pragma unroll
        for (int j = 0; j < 5; ++j)
            g[j] = *reinterpret_cast<const s16x8*>(wbf + GT + goff[j] + d);
        f32x2 s[4];
        cvt8(g[0], s);
        #pragma unroll
        for (int j = 1; j < 5; ++j) {
            f32x2 t[4];
            cvt8(g[j], t);
            #pragma unroll
            for (int h = 0; h < 4; ++h) s[h] += t[h];
        }
        u32x4 wv;
        #pragma unroll
        for (int h = 0; h < 4; ++h)
            wv[h] = pk2(fmaxf(s[h][0], 0.f), fmaxf(s[h][1], 0.f));
        *reinterpret_cast<u32x4*>(smem + BA + SWZ(p1row * 512 + c8 * 16, p1row)) = wv;
    }
    __syncthreads();

    // ---------- GEMM2 part A (ks 0..7 from buf A) + phase 1b (dims [256,512) -> buf B)
    f32x4 acc2[4][2];
    #pragma unroll
    for (int rt = 0; rt < 4; ++rt)
        #pragma unroll
        for (int ct = 0; ct < 2; ++ct) acc2[rt][ct] = (f32x4){0.f, 0.f, 0.f, 0.f};
    {
        #pragma unroll
        for (int it = 0; it < 4; ++it) {
            const int c8 = it * 8 + p1c;
            const int d  = 256 + c8 * 8;
            s16x8 g[5];
            #pragma unroll
            for (int j = 0; j < 5; ++j)
                g[j] = *reinterpret_cast<const s16x8*>(wbf + GT + goff[j] + d);
            f32x2 s[4];
            cvt8(g[0], s);
            #pragma unroll
            for (int j = 1; j < 5; ++j) {
                f32x2 t[4];
                cvt8(g[j], t);
                #pragma unroll
                for (int h = 0; h < 4; ++h) s[h] += t[h];
            }
            u32x4 wv;
            #pragma unroll
            for (int h = 0; h < 4; ++h)
                wv[h] = pk2(fmaxf(s[h][0], 0.f), fmaxf(s[h][1], 0.f));
            *reinterpret_cast<u32x4*>(smem + BB + SWZ(p1row * 512 + c8 * 16, p1row)) = wv;
        }
        for (int ks = 0; ks < 8; ++ks) {
            s16x8 xv[4];
            #pragma unroll
            for (int rt = 0; rt < 4; ++rt) {
                const int row = rt * 16 + l15;
                xv[rt] = *reinterpret_cast<const s16x8*>(
                    smem + BA + SWZ(row * 512 + ks * 64 + l4 * 16, row));
            }
            __builtin_amdgcn_s_setprio(1);
            #pragma unroll
            for (int ct = 0; ct < 2; ++ct) {
                const s16x8 w = *reinterpret_cast<const s16x8*>(
                    wbf + W2P + (((wave * 2 + ct) * 16 + ks) * 64 + lane) * 8);
                #pragma unroll
                for (int rt = 0; rt < 4; ++rt)
                    acc2[rt][ct] = __builtin_amdgcn_mfma_f32_16x16x32_bf16(w, xv[rt], acc2[rt][ct], 0, 0, 0);
            }
            __builtin_amdgcn_s_setprio(0);
        }
    }
    __syncthreads();

    // ---------- GEMM2 part B (ks 8..15 from buf B) + epilogue -> h2 in buf A
    {
        for (int ks = 0; ks < 8; ++ks) {
            s16x8 xv[4];
            #pragma unroll
            for (int rt = 0; rt < 4; ++rt) {
                const int row = rt * 16 + l15;
                xv[rt] = *reinterpret_cast<const s16x8*>(
                    smem + BB + SWZ(row * 512 + ks * 64 + l4 * 16, row));
            }
            __builtin_amdgcn_s_setprio(1);
            #pragma unroll
            for (int ct = 0; ct < 2; ++ct) {
                const s16x8 w = *reinterpret_cast<const s16x8*>(
                    wbf + W2P + (((wave * 2 + ct) * 16 + 8 + ks) * 64 + lane) * 8);
                #pragma unroll
                for (int rt = 0; rt < 4; ++rt)
                    acc2[rt][ct] = __builtin_amdgcn_mfma_f32_16x16x32_bf16(w, xv[rt], acc2[rt][ct], 0, 0, 0);
            }
            __builtin_amdgcn_s_setprio(0);
        }
        #pragma unroll
        for (int ct = 0; ct < 2; ++ct) {
            const int col0 = (wave * 2 + ct) * 16 + l4 * 4;
            const float4 bb = *reinterpret_cast<const float4*>(b2 + col0);
            #pragma unroll
            for (int rt = 0; rt < 4; ++rt) {
                const int row = rt * 16 + l15;
                *reinterpret_cast<u32x2*>(smem + BA + SWZ(row * 512 + col0 * 2, row)) =
                    pack_relu(acc2[rt][ct], bb);
            }
        }
    }
    __syncthreads();

    // ---------- GEMM3: [64,256] -> [64,128]; wave=ct, 4 row-tiles; h3 -> buf B
    {
        f32x4 acc[4];
        #pragma unroll
        for (int rt = 0; rt < 4; ++rt) acc[rt] = (f32x4){0.f, 0.f, 0.f, 0.f};
        for (int ks = 0; ks < 8; ++ks) {
            const s16x8 w = *reinterpret_cast<const s16x8*>(
                wbf + W3P + ((wave * 8 + ks) * 64 + lane) * 8);
            s16x8 xv[4];
            #pragma unroll
            for (int rt = 0; rt < 4; ++rt) {
                const int row = rt * 16 + l15;
                xv[rt] = *reinterpret_cast<const s16x8*>(
                    smem + BA + SWZ(row * 512 + ks * 64 + l4 * 16, row));
            }
            __builtin_amdgcn_s_setprio(1);
            #pragma unroll
            for (int rt = 0; rt < 4; ++rt)
                acc[rt] = __builtin_amdgcn_mfma_f32_16x16x32_bf16(w, xv[rt], acc[rt], 0, 0, 0);
            __builtin_amdgcn_s_setprio(0);
        }
        const int col0 = wave * 16 + l4 * 4;
        const float4 bb = *reinterpret_cast<const float4*>(b3 + col0);
        #pragma unroll
        for (int rt = 0; rt < 4; ++rt) {
            const int row = rt * 16 + l15;
            *reinterpret_cast<u32x2*>(smem + BB + SWZ(row * 256 + col0 * 2, row)) =
                pack_relu(acc[rt], bb);
        }
    }
    __syncthreads();

    // ---------- GEMM4: [64,128] -> out[64,38]; 12 tasks over 8 waves
    for (int task = wave; task < 12; task += 8) {
        const int mt = task >> 2;
        const int rt = task & 3;
        f32x4 acc = (f32x4){0.f, 0.f, 0.f, 0.f};
        #pragma unroll
        for (int ks = 0; ks < 4; ++ks) {
            const int row = rt * 16 + l15;
            const s16x8 xv = *reinterpret_cast<const s16x8*>(
                smem + BB + SWZ(row * 256 + ks * 64 + l4 * 16, row));
            const s16x8 w = *reinterpret_cast<const s16x8*>(
                wbf + W4P + ((mt * 4 + ks) * 64 + lane) * 8);
            acc = __builtin_amdgcn_mfma_f32_16x16x32_bf16(w, xv, acc, 0, 0, 0);
        }
        const int rg   = r0 + rt * 16 + l15;
        const int col0 = mt * 16 + l4 * 4;
        #pragma unroll
        for (int h = 0; h < 2; ++h) {
            const int c = col0 + 2 * h;
            if (c < 38) {
                f32x2 v;
                v[0] = acc[2 * h]     + b4[c];
                v[1] = acc[2 * h + 1] + b4[c + 1];
                *reinterpret_cast<f32x2*>(out + rg * 38 + c) = v;
            }
        }
    }
}

extern "C" void kernel_launch(void* const* d_in, const int* in_sizes, int n_in,
                              void* d_out, int out_size, void* d_ws, size_t ws_size,
                              hipStream_t stream) {
    const int*   tok = (const int*)d_in[0];
    const float* emb = (const float*)d_in[1];
    const float* W1  = (const float*)d_in[2];
    const float* b1  = (const float*)d_in[3];
    const float* W2  = (const float*)d_in[4];
    const float* b2  = (const float*)d_in[5];
    const float* W3  = (const float*)d_in[6];
    const float* b3  = (const float*)d_in[7];
    const float* W4  = (const float*)d_in[8];
    const float* b4  = (const float*)d_in[9];
    float* out = (float*)d_out;
    unsigned short* wbf = (unsigned short*)d_ws;

    const int pack_blocks = (FTOT * 64 + 511) / 512;     // 42
    prep<<<195 + pack_blocks, 512, 0, stream>>>(W1, W2, W3, W4, emb, b1, wbf);
    fused_mlp<<<1024, 512, 0, stream>>>(tok, wbf, b2, b3, b4, out);
}